// Round 5
// baseline (265.136 us; speedup 1.0000x reference)
//
#include <hip/hip_runtime.h>

// Problem constants (B, N, D fixed by the reference)
#define B_ 32
#define N_ 4096
#define D_ 256
#define K_ 2048            // max(1, int(N * (1 - 0.5)))

// Rank-kernel tiling
#define ISPLIT 2                    // i-chunks per batch (2048 elements each)
#define JSPLIT 8                    // j-chunks per batch (512 keys each)
#define EPT 8                       // i-elements per thread (contiguous)
#define JSLICE (N_ / JSPLIT)        // 512 keys staged in LDS per block

// ---------------------------------------------------------------------------
// Kernel 1: compute the 64-bit sort key for every (b, i); zero rankBuf (u64
// stores) and meanAccum (ws is poisoned each launch).
// Key = (orderable(f32 noisy) << 32) | ~index  -> larger key == earlier in
// descending top-k order, ties broken by LOWER index (matches lax.top_k).
// Bit-identical to the round-0 (passing) kernel's key computation.
// ---------------------------------------------------------------------------
__global__ __launch_bounds__(256) void key_kernel(
    const float* __restrict__ attn, const float* __restrict__ noise,
    unsigned long long* __restrict__ keys,
    unsigned long long* __restrict__ rankBuf64,
    float* __restrict__ meanAccum) {
  const int t = blockIdx.x * 256 + threadIdx.x;   // 0 .. B*N-1
  float u = noise[t];
  float a = attn[t];
  float x = __fadd_rn(u, 1e-10f);              // u + 1e-10
  float l1 = (float)log((double)x);            // ~correctly-rounded f32 log
  float inner = __fadd_rn(-l1, 1e-10f);        // -log(u+1e-10) + 1e-10
  float g = -(float)log((double)inner);        // gumbel
  float noisy = __fadd_rn(a, __fmul_rn(0.1f, g));  // attn + 0.1*g (no FMA)
  unsigned int fb = __float_as_uint(noisy);
  fb = (fb & 0x80000000u) ? ~fb : (fb | 0x80000000u);  // orderable f32
  int i = t & (N_ - 1);
  keys[t] = ((unsigned long long)fb << 32) | (unsigned int)(~i);
  if (t < B_ * N_ / 4) rankBuf64[t] = 0ull;    // zero u16 rank buffer
  if (t < B_ * D_) meanAccum[t] = 0.0f;
}

// ---------------------------------------------------------------------------
// Kernel 2: tiled partial rank-by-count (round-4 structure, proven).
// Block (ic, jc, b): ranks 2048 i-elements (EPT=8 CONTIGUOUS per thread,
// register-held keys) against a 512-key j-slice staged once in LDS.
// Inner loop: one broadcast ds_read_b128 (2 keys, ~12 DS cyc) feeds 32 VALU
// inst (~64 cyc) -> VALU-bound. 512 blocks = 8 waves/CU.
// Merge: 8 u16 partial ranks packed into 2 u64 atomicAdds (4x u16 fields;
// max total per field 4095 -> no cross-field carry). 256k atomics total
// (was 1M u32 in round 4).
// VALU floor: B*N*N compares * 2 inst / 64 lanes / 1024 SIMDs ~ 14 us.
// ---------------------------------------------------------------------------
__global__ __launch_bounds__(256) void rank_kernel(
    const unsigned long long* __restrict__ keys,
    unsigned long long* __restrict__ rankBuf64) {
  const int b = blockIdx.y;
  const int ic = blockIdx.x >> 3;          // 0..ISPLIT-1
  const int jc = blockIdx.x & (JSPLIT - 1);
  __shared__ __align__(16) ulonglong2 lk2[JSLICE / 2];  // 4 KiB

  const unsigned long long* __restrict__ bk = keys + (size_t)b * N_;

  // stage the j-slice (one ulonglong2 per thread)
  const ulonglong2* __restrict__ gk2 = (const ulonglong2*)(bk + jc * JSLICE);
  lk2[threadIdx.x] = gk2[threadIdx.x];     // JSLICE/2 == 256 == blockDim

  // this thread's EPT contiguous i-keys; a wave covers a contiguous 4 KB
  // span via 4x global_load_dwordx4 per lane (coalesced).
  const int ibase = ic * (N_ / ISPLIT) + threadIdx.x * EPT;
  unsigned long long ki[EPT];
  const ulonglong2* __restrict__ gi2 = (const ulonglong2*)(bk + ibase);
#pragma unroll
  for (int e2 = 0; e2 < EPT / 2; ++e2) {
    ulonglong2 v = gi2[e2];
    ki[2 * e2] = v.x;
    ki[2 * e2 + 1] = v.y;
  }
  __syncthreads();

  unsigned int rk[EPT] = {0u, 0u, 0u, 0u, 0u, 0u, 0u, 0u};
#pragma unroll 4
  for (int j = 0; j < JSLICE / 2; ++j) {
    ulonglong2 v = lk2[j];                 // broadcast read, conflict-free
#pragma unroll
    for (int e = 0; e < EPT; ++e) {
      rk[e] += (v.x > ki[e]);
      rk[e] += (v.y > ki[e]);
    }
  }

  // pack 8 u16 partial ranks -> 2 u64 atomic adds (little-endian field order
  // matches the u16 array layout)
  unsigned long long p0 =
      (unsigned long long)rk[0] | ((unsigned long long)rk[1] << 16) |
      ((unsigned long long)rk[2] << 32) | ((unsigned long long)rk[3] << 48);
  unsigned long long p1 =
      (unsigned long long)rk[4] | ((unsigned long long)rk[5] << 16) |
      ((unsigned long long)rk[6] << 32) | ((unsigned long long)rk[7] << 48);
  const size_t q = ((size_t)b * N_ + ibase) >> 2;   // u64 index (ibase % 4 == 0)
  atomicAdd(&rankBuf64[q], p0);
  atomicAdd(&rankBuf64[q + 1], p1);
}

// ---------------------------------------------------------------------------
// Kernel 3: scatter sortedIdx[b][rank] = i, plus fused pruned-row mean
// accumulation (threads whose rank >= K collect their row index into an LDS
// list; the whole block then gathers those seq rows with float4 loads).
// ---------------------------------------------------------------------------
__global__ __launch_bounds__(256) void scatter_mean_kernel(
    const unsigned short* __restrict__ rankBuf16, const float* __restrict__ seq,
    int* __restrict__ sortedIdx, float* __restrict__ meanAccum) {
  const int b = blockIdx.y;
  const int i = blockIdx.x * 256 + threadIdx.x;   // grid.x = 16
  const unsigned int rank = rankBuf16[(size_t)b * N_ + i];
  sortedIdx[(size_t)b * N_ + rank] = i;

  __shared__ int plist[256];
  __shared__ int pcount;
  if (threadIdx.x == 0) pcount = 0;
  __syncthreads();
  if (rank >= K_) {
    int slot = atomicAdd(&pcount, 1);
    plist[slot] = i;
  }
  __syncthreads();
  const int cnt = pcount;

  const int dv = threadIdx.x & 63;        // float4 column 0..63
  const int sub = threadIdx.x >> 6;       // row subgroup 0..3
  float4 acc = make_float4(0.f, 0.f, 0.f, 0.f);
  for (int r = sub; r < cnt; r += 4) {
    const float4* row = (const float4*)(seq + ((size_t)b * N_ + plist[r]) * D_);
    float4 v = row[dv];
    acc.x += v.x; acc.y += v.y; acc.z += v.z; acc.w += v.w;
  }

  __shared__ float4 red[4][64];
  red[sub][dv] = acc;
  __syncthreads();
  if (sub == 0) {
    float4 s0 = red[0][dv], s1 = red[1][dv], s2 = red[2][dv], s3 = red[3][dv];
    float sx = s0.x + s1.x + s2.x + s3.x;
    float sy = s0.y + s1.y + s2.y + s3.y;
    float sz = s0.z + s1.z + s2.z + s3.z;
    float sw = s0.w + s1.w + s2.w + s3.w;
    float* dst = meanAccum + b * D_ + dv * 4;
    atomicAdd(dst + 0, sx);
    atomicAdd(dst + 1, sy);
    atomicAdd(dst + 2, sz);
    atomicAdd(dst + 3, sw);
  }
}

// ---------------------------------------------------------------------------
// Kernel 4: out[b][j][d] = seq[b][top_idx[b][j]][d] + 0.05 * (sum[b][d]/2048)
// One float4 per thread; flat thread id == flat float4 output index.
// Already at the 128 MB / 6.3 TB/s ~ 21 us roofline.
// ---------------------------------------------------------------------------
__global__ __launch_bounds__(256) void out_kernel(
    const float* __restrict__ seq, const int* __restrict__ sortedIdx,
    const float* __restrict__ meanAccum, float* __restrict__ out) {
  const unsigned int t = blockIdx.x * 256u + threadIdx.x;  // < B*K*D/4 = 4194304
  const int dv = t & 63;                 // float4 column
  const int j = (t >> 6) & (K_ - 1);     // rank within top-k
  const int b = t >> 17;                 // batch

  int idx = sortedIdx[b * N_ + j];
  float4 v = ((const float4*)(seq + ((size_t)b * N_ + idx) * D_))[dv];
  float4 m = ((const float4*)(meanAccum + b * D_))[dv];
  const float inv_cnt = 1.0f / 2048.0f;  // count = 2048 (+1e-10 is sub-ulp)
  float4 o;
  o.x = v.x + 0.05f * (m.x * inv_cnt);
  o.y = v.y + 0.05f * (m.y * inv_cnt);
  o.z = v.z + 0.05f * (m.z * inv_cnt);
  o.w = v.w + 0.05f * (m.w * inv_cnt);
  ((float4*)out)[t] = o;
}

// ---------------------------------------------------------------------------
extern "C" void kernel_launch(void* const* d_in, const int* in_sizes, int n_in,
                              void* d_out, int out_size, void* d_ws, size_t ws_size,
                              hipStream_t stream) {
  const float* seq  = (const float*)d_in[0];
  const float* attn = (const float*)d_in[1];
  const float* nois = (const float*)d_in[2];
  float* out = (float*)d_out;

  // workspace layout (1.78 MiB total)
  int* sortedIdx   = (int*)d_ws;                                        // 512 KiB
  float* meanAccum = (float*)((char*)d_ws + (size_t)B_ * N_ * 4);       // 32 KiB
  unsigned long long* keys =
      (unsigned long long*)((char*)d_ws + (size_t)B_ * N_ * 4 + (size_t)B_ * D_ * 4);  // 1 MiB
  unsigned long long* rankBuf64 =
      (unsigned long long*)((char*)keys + (size_t)B_ * N_ * 8);         // 256 KiB (u16[B*N])
  unsigned short* rankBuf16 = (unsigned short*)rankBuf64;

  key_kernel<<<(B_ * N_) / 256, 256, 0, stream>>>(attn, nois, keys, rankBuf64, meanAccum);
  rank_kernel<<<dim3(ISPLIT * JSPLIT, B_), 256, 0, stream>>>(keys, rankBuf64);
  scatter_mean_kernel<<<dim3(N_ / 256, B_), 256, 0, stream>>>(rankBuf16, seq, sortedIdx, meanAccum);
  const int total4 = B_ * K_ * (D_ / 4);   // 4,194,304
  out_kernel<<<total4 / 256, 256, 0, stream>>>(seq, sortedIdx, meanAccum, out);
}

// Round 6
// 261.934 us; speedup vs baseline: 1.0122x; 1.0122x over previous
//
#include <hip/hip_runtime.h>

// Problem constants (B, N, D fixed by the reference)
#define B_ 32
#define N_ 4096
#define D_ 256
#define K_ 2048            // max(1, int(N * (1 - 0.5)))

// Rank-kernel tiling: 1024 blocks = 4 waves/SIMD (TLP for the cmp/addc chains)
#define ISPLIT 2                    // i-chunks per batch (2048 elements each)
#define JSPLIT 16                   // j-chunks per batch (256 keys each)
#define EPT 8                       // i-elements per thread (contiguous)
#define JSLICE (N_ / JSPLIT)        // 256 keys staged in LDS per block

// ---------------------------------------------------------------------------
// Kernel 1: compute the 64-bit sort key for every (b, i); zero rankBuf (u64
// stores) and meanAccum (ws is poisoned each launch).
// Key = (orderable(f32 noisy) << 32) | ~index  -> larger key == earlier in
// descending top-k order, ties broken by LOWER index (matches lax.top_k).
// Bit-identical to the round-0 (passing) kernel's key computation.
// ---------------------------------------------------------------------------
__global__ __launch_bounds__(256) void key_kernel(
    const float* __restrict__ attn, const float* __restrict__ noise,
    unsigned long long* __restrict__ keys,
    unsigned long long* __restrict__ rankBuf64,
    float* __restrict__ meanAccum) {
  const int t = blockIdx.x * 256 + threadIdx.x;   // 0 .. B*N-1
  float u = noise[t];
  float a = attn[t];
  float x = __fadd_rn(u, 1e-10f);              // u + 1e-10
  float l1 = (float)log((double)x);            // ~correctly-rounded f32 log
  float inner = __fadd_rn(-l1, 1e-10f);        // -log(u+1e-10) + 1e-10
  float g = -(float)log((double)inner);        // gumbel
  float noisy = __fadd_rn(a, __fmul_rn(0.1f, g));  // attn + 0.1*g (no FMA)
  unsigned int fb = __float_as_uint(noisy);
  fb = (fb & 0x80000000u) ? ~fb : (fb | 0x80000000u);  // orderable f32
  int i = t & (N_ - 1);
  keys[t] = ((unsigned long long)fb << 32) | (unsigned int)(~i);
  if (t < B_ * N_ / 4) rankBuf64[t] = 0ull;    // zero u16 rank buffer
  if (t < B_ * D_) meanAccum[t] = 0.0f;
}

// ---------------------------------------------------------------------------
// Kernel 2: tiled partial rank-by-count.
// Block (ic, jc, b): ranks 2048 i-elements (EPT=8 contiguous per thread,
// register-held) against a 256-key j-slice staged in LDS. 1024 blocks =
// 4 waves/SIMD (double round-5's TLP to cover the vcc dependency chains).
// Balance per CU: DS = 16 waves x 128 ds_read_b128 x 12cyc = 24.6k cyc,
// VALU per SIMD = 4 waves x 8192 cyc = 32.8k cyc -> still VALU-bound.
// Merge: 8 u16 partial ranks packed into 2 u64 atomicAdds (max per field
// 4095 -> no carry-out). VALU floor ~ 14 us chip-wide.
// ---------------------------------------------------------------------------
__global__ __launch_bounds__(256) void rank_kernel(
    const unsigned long long* __restrict__ keys,
    unsigned long long* __restrict__ rankBuf64) {
  const int b = blockIdx.y;
  const int ic = blockIdx.x >> 4;          // 0..ISPLIT-1
  const int jc = blockIdx.x & (JSPLIT - 1);
  __shared__ __align__(16) unsigned long long lk[JSLICE];  // 2 KiB

  const unsigned long long* __restrict__ bk = keys + (size_t)b * N_;

  // stage the j-slice (one u64 per thread, coalesced)
  lk[threadIdx.x] = bk[jc * JSLICE + threadIdx.x];

  // this thread's EPT contiguous i-keys; the wave covers a contiguous 4 KB
  // span via 4x global_load_dwordx4 per lane.
  const int ibase = ic * (N_ / ISPLIT) + threadIdx.x * EPT;
  unsigned long long ki[EPT];
  const ulonglong2* __restrict__ gi2 = (const ulonglong2*)(bk + ibase);
#pragma unroll
  for (int e2 = 0; e2 < EPT / 2; ++e2) {
    ulonglong2 v = gi2[e2];
    ki[2 * e2] = v.x;
    ki[2 * e2 + 1] = v.y;
  }
  __syncthreads();

  const ulonglong2* lk2 = (const ulonglong2*)lk;
  unsigned int rk[EPT] = {0u, 0u, 0u, 0u, 0u, 0u, 0u, 0u};
#pragma unroll 4
  for (int j = 0; j < JSLICE / 2; ++j) {
    ulonglong2 v = lk2[j];                 // broadcast read, conflict-free
#pragma unroll
    for (int e = 0; e < EPT; ++e) {
      rk[e] += (v.x > ki[e]);
      rk[e] += (v.y > ki[e]);
    }
  }

  unsigned long long p0 =
      (unsigned long long)rk[0] | ((unsigned long long)rk[1] << 16) |
      ((unsigned long long)rk[2] << 32) | ((unsigned long long)rk[3] << 48);
  unsigned long long p1 =
      (unsigned long long)rk[4] | ((unsigned long long)rk[5] << 16) |
      ((unsigned long long)rk[6] << 32) | ((unsigned long long)rk[7] << 48);
  const size_t q = ((size_t)b * N_ + ibase) >> 2;   // u64 index (ibase % 4 == 0)
  atomicAdd(&rankBuf64[q], p0);
  atomicAdd(&rankBuf64[q + 1], p1);
}

// ---------------------------------------------------------------------------
// Kernel 3: pruned-row mean accumulation, reading ranks directly (no
// sortedIdx round-trip). Grid (32, B) = 1024 blocks, 128 i's per block.
// Threads < 128 collect pruned indices into an LDS list; then 4 x 64-lane
// wave-groups gather the rows (1 KB coalesced each) and reduce.
// ---------------------------------------------------------------------------
__global__ __launch_bounds__(256) void mean_kernel(
    const unsigned short* __restrict__ rankBuf16, const float* __restrict__ seq,
    float* __restrict__ meanAccum) {
  const int b = blockIdx.y;
  const int ibase = blockIdx.x * 128;       // grid.x = 32
  __shared__ int plist[128];
  __shared__ int pcount;
  if (threadIdx.x == 0) pcount = 0;
  __syncthreads();
  if (threadIdx.x < 128) {
    const int i = ibase + threadIdx.x;
    const unsigned int rank = rankBuf16[(size_t)b * N_ + i];
    if (rank >= K_) {
      int slot = atomicAdd(&pcount, 1);
      plist[slot] = i;
    }
  }
  __syncthreads();
  const int cnt = pcount;

  const int dv = threadIdx.x & 63;        // float4 column 0..63
  const int sub = threadIdx.x >> 6;       // wave-group 0..3
  float4 acc = make_float4(0.f, 0.f, 0.f, 0.f);
  for (int r = sub; r < cnt; r += 4) {
    const float4* row = (const float4*)(seq + ((size_t)b * N_ + plist[r]) * D_);
    float4 v = row[dv];
    acc.x += v.x; acc.y += v.y; acc.z += v.z; acc.w += v.w;
  }

  __shared__ float4 red[4][64];
  red[sub][dv] = acc;
  __syncthreads();
  if (sub == 0) {
    float4 s0 = red[0][dv], s1 = red[1][dv], s2 = red[2][dv], s3 = red[3][dv];
    float sx = s0.x + s1.x + s2.x + s3.x;
    float sy = s0.y + s1.y + s2.y + s3.y;
    float sz = s0.z + s1.z + s2.z + s3.z;
    float sw = s0.w + s1.w + s2.w + s3.w;
    float* dst = meanAccum + b * D_ + dv * 4;
    atomicAdd(dst + 0, sx);
    atomicAdd(dst + 1, sy);
    atomicAdd(dst + 2, sz);
    atomicAdd(dst + 3, sw);
  }
}

// ---------------------------------------------------------------------------
// Kernel 4: scatter-style output, reading ranks directly.
// Grid (32, B) = 1024 blocks, 128 i's per block. Selected (rank < K) rows are
// collected into an LDS list; 4 x 64-lane wave-groups then copy each row:
// out[b][rank][:] = seq[b][i][:] + 0.05 * mean  (1 KB coalesced read AND
// write per row). Ranks are a permutation -> every out row written once.
// ---------------------------------------------------------------------------
__global__ __launch_bounds__(256) void out_kernel(
    const unsigned short* __restrict__ rankBuf16, const float* __restrict__ seq,
    const float* __restrict__ meanAccum, float* __restrict__ out) {
  const int b = blockIdx.y;
  const int ibase = blockIdx.x * 128;       // grid.x = 32
  __shared__ int pl_i[128];
  __shared__ unsigned short pl_r[128];
  __shared__ int pcount;
  if (threadIdx.x == 0) pcount = 0;
  __syncthreads();
  if (threadIdx.x < 128) {
    const int i = ibase + threadIdx.x;
    const unsigned int rank = rankBuf16[(size_t)b * N_ + i];
    if (rank < K_) {
      int slot = atomicAdd(&pcount, 1);
      pl_i[slot] = i;
      pl_r[slot] = (unsigned short)rank;
    }
  }
  __syncthreads();
  const int cnt = pcount;

  const int dv = threadIdx.x & 63;        // float4 column 0..63
  const int sub = threadIdx.x >> 6;       // wave-group 0..3
  float4 m = ((const float4*)(meanAccum + b * D_))[dv];
  const float s = 0.05f * (1.0f / 2048.0f);  // count = 2048 (+1e-10 is sub-ulp)
  float4 mix;
  mix.x = m.x * s; mix.y = m.y * s; mix.z = m.z * s; mix.w = m.w * s;

  for (int r = sub; r < cnt; r += 4) {
    const float4* row = (const float4*)(seq + ((size_t)b * N_ + pl_i[r]) * D_);
    float4 v = row[dv];
    float4 o;
    o.x = v.x + mix.x; o.y = v.y + mix.y; o.z = v.z + mix.z; o.w = v.w + mix.w;
    ((float4*)(out + ((size_t)b * K_ + pl_r[r]) * D_))[dv] = o;
  }
}

// ---------------------------------------------------------------------------
extern "C" void kernel_launch(void* const* d_in, const int* in_sizes, int n_in,
                              void* d_out, int out_size, void* d_ws, size_t ws_size,
                              hipStream_t stream) {
  const float* seq  = (const float*)d_in[0];
  const float* attn = (const float*)d_in[1];
  const float* nois = (const float*)d_in[2];
  float* out = (float*)d_out;

  // workspace layout (1.28 MiB total; sortedIdx eliminated)
  float* meanAccum = (float*)d_ws;                                      // 32 KiB
  unsigned long long* keys =
      (unsigned long long*)((char*)d_ws + (size_t)B_ * D_ * 4);         // 1 MiB
  unsigned long long* rankBuf64 =
      (unsigned long long*)((char*)keys + (size_t)B_ * N_ * 8);         // 256 KiB (u16[B*N])
  unsigned short* rankBuf16 = (unsigned short*)rankBuf64;

  key_kernel<<<(B_ * N_) / 256, 256, 0, stream>>>(attn, nois, keys, rankBuf64, meanAccum);
  rank_kernel<<<dim3(ISPLIT * JSPLIT, B_), 256, 0, stream>>>(keys, rankBuf64);
  mean_kernel<<<dim3(32, B_), 256, 0, stream>>>(rankBuf16, seq, meanAccum);
  out_kernel<<<dim3(32, B_), 256, 0, stream>>>(rankBuf16, seq, meanAccum, out);
}